// Round 5
// baseline (81.115 us; speedup 1.0000x reference)
//
#include <hip/hip_runtime.h>

// SimpleSNN: out[r][j] = sum over 10 steps of spikes from a leaky neuron driven by
// cur[r][j] = dot(x[r,:], W[j,:]).  x:[65536,784] f32, W:[10,784] f32, out f32.
//
// R5 = R3 structure (LDS-staged coalesced x, thread-per-row, 8-way col split) with
// the stall sources amortized:
//  - R4 proved per-lane row streaming is uncoalesced poison (68us). Reverted.
//  - TW 16 -> 56: 14 barriers/block instead of 49; 70 f64 FMA between lgkm waits
//    instead of 20 (ds_read and s_load share lgkmcnt; longer FMA runs amortize
//    the conservative waits).
//  - W transposed + f64 (W64T[c][j]) so each tile/wave W block = 560B contiguous
//    imm-offset s_loads.
//  - LDS union: x dbuf 2*64*57*4 = 29.2KB / combine 8*64*10*8 = 40KB -> 40KB,
//    4 blocks/CU x 8 waves = 32 waves/CU.
//  - f64 products/accumulation/recurrence unchanged (absmax==0 in R1/R3/R4;
//    threshold crossings mem>1.0 are the correctness hazard).

constexpr int ROWS  = 65536;
constexpr int COLS  = 784;
constexpr int NOUT  = 10;
constexpr int STEPS = 10;

constexpr int BR   = 64;          // rows per block (thread r owns one row)
constexpr int TW   = 56;          // tile width (784 = 14*56)
constexpr int NT   = COLS / TW;   // 14 tiles -> 14 barriers
constexpr int PADW = TW + 1;      // 57: odd stride -> conflict-free b32 row reads
constexpr int NH   = 8;           // column octants (= waves per block)
constexpr int CPH  = TW / NH;     // 7 cols per thread per tile
constexpr int NF4  = BR * TW / 4; // 896 float4 per tile

__global__ void w_prep(const float* __restrict__ W, double* __restrict__ W64T) {
    int i = blockIdx.x * 256 + threadIdx.x;   // i = c*10 + j
    if (i < NOUT * COLS) {
        int c = i / NOUT, j = i - c * NOUT;
        W64T[i] = (double)W[(size_t)j * COLS + c];
    }
}

__global__ __launch_bounds__(512, 8)
void snn_fused(const float* __restrict__ x, const double* __restrict__ W64T,
               float* __restrict__ out) {
    // union: [2][BR][PADW] f32 x-tiles (29184B) / [NH][BR][NOUT] f64 combine (40960B)
    __shared__ __align__(16) char smem[NH * BR * NOUT * 8];
    float*  tile = reinterpret_cast<float*>(smem);
    double* comb = reinterpret_cast<double*>(smem);

    const int tid  = threadIdx.x;
    const int r    = tid & (BR - 1);
    const int hu   = __builtin_amdgcn_readfirstlane(tid >> 6);  // wave id = col octant
    const size_t row0 = (size_t)blockIdx.x * BR;

    const float* xblk = x + row0 * COLS;

    // staging: 896 float4 per tile (64 rows x 56 cols); 512 threads, <=2 each.
    float4 cv[2];
    auto issue = [&](int t, float4* v) {
        const float* xb = xblk + t * TW;
        #pragma unroll
        for (int k = 0; k < 2; ++k) {
            int i = tid + 512 * k;
            if (i < NF4) {
                int rr = i / (TW / 4), c4 = i % (TW / 4);
                v[k] = *reinterpret_cast<const float4*>(xb + (size_t)rr * COLS + c4 * 4);
            }
        }
    };
    auto wlds = [&](int b, const float4* v) {
        float* dst = tile + b * (BR * PADW);
        #pragma unroll
        for (int k = 0; k < 2; ++k) {
            int i = tid + 512 * k;
            if (i < NF4) {
                int rr = i / (TW / 4), c4 = i % (TW / 4);
                float* p = dst + rr * PADW + c4 * 4;
                p[0] = v[k].x; p[1] = v[k].y; p[2] = v[k].z; p[3] = v[k].w;
            }
        }
    };

    double acc[NOUT];
    #pragma unroll
    for (int j = 0; j < NOUT; ++j) acc[j] = 0.0;

    issue(0, cv);
    wlds(0, cv);
    __syncthreads();

    for (int t = 0; t < NT; ++t) {
        float4 nv[2];
        if (t + 1 < NT) issue(t + 1, nv);       // HBM latency under compute

        const float*  src = tile + (t & 1) * (BR * PADW) + r * PADW + hu * CPH;
        const double* wb  = W64T + (size_t)(t * TW + hu * CPH) * NOUT;  // 560B contiguous
        #pragma unroll
        for (int c = 0; c < CPH; ++c) {
            double xd = (double)src[c];         // ds_read_b32 + cvt (1 per 10 FMA)
            #pragma unroll
            for (int j = 0; j < NOUT; ++j)
                acc[j] = fma(xd, wb[c * NOUT + j], acc[j]);
        }

        if (t + 1 < NT) wlds((t + 1) & 1, nv);  // vmcnt wait lands here
        __syncthreads();                        // 1 barrier per tile (14 total)
    }

    // combine 8 octant-partials per (row, j), then run the recurrence
    #pragma unroll
    for (int j = 0; j < NOUT; ++j)
        comb[(hu * BR + r) * NOUT + j] = acc[j];
    __syncthreads();

    for (int i = tid; i < BR * NOUT; i += 512) {   // 640 outputs, 512 threads
        double c0 = comb[i]                  + comb[BR * NOUT + i];
        double c1 = comb[2 * BR * NOUT + i]  + comb[3 * BR * NOUT + i];
        double c2 = comb[4 * BR * NOUT + i]  + comb[5 * BR * NOUT + i];
        double c3 = comb[6 * BR * NOUT + i]  + comb[7 * BR * NOUT + i];
        double cur = (c0 + c1) + (c2 + c3);

        double mem = 0.0, spk = 0.0, s = 0.0;
        #pragma unroll
        for (int st = 0; st < STEPS; ++st) {
            mem = 0.95 * mem + cur - spk;       // reset-by-subtraction, thr=1.0
            spk = (mem > 1.0) ? 1.0 : 0.0;
            s  += spk;
        }
        out[row0 * NOUT + i] = (float)s;        // 2560B coalesced per block
    }
}

extern "C" void kernel_launch(void* const* d_in, const int* in_sizes, int n_in,
                              void* d_out, int out_size, void* d_ws, size_t ws_size,
                              hipStream_t stream) {
    const float* x = (const float*)d_in[0];
    const float* W = (const float*)d_in[1];
    float*  out  = (float*)d_out;
    double* W64T = (double*)d_ws;   // 7840 * 8B = 62.7 KB

    hipLaunchKernelGGL(w_prep, dim3((NOUT * COLS + 255) / 256), dim3(256), 0, stream, W, W64T);
    hipLaunchKernelGGL(snn_fused, dim3(ROWS / BR), dim3(512), 0, stream, x, W64T, out);
}

// Round 6
// 48.920 us; speedup vs baseline: 1.6581x; 1.6581x over previous
//
#include <hip/hip_runtime.h>

// SimpleSNN: out[r][j] = sum over 10 steps of spikes from a leaky neuron driven by
// cur[r][j] = dot(x[r,:], W[j,:]).  x:[65536,784] f32, W:[10,784] f32, out f32.
//
// R6 = R3 geometry (TW=16: 20 W-doubles/tile = 40 SGPRs, fits the ~102-SGPR wave
// budget -- R5's TW=56 needed 140 SGPRs and regressed 48->81us) plus a depth-3
// prefetch pipeline:
//  - registers hold tiles t+1 (rA) and t+2 (rB); issue t+3 (rC) each iteration.
//    wlds(t+1) therefore waits on a load issued TWO iterations (~1800cy of block
//    work) earlier; compiler emits a counted vmcnt leaving younger loads in flight.
//    R3 was depth-1: vmcnt(0) on a ~90cy-old load = ~500cy stall per tile.
//  - 1 barrier/tile: writes go one tile ahead into the ping-pong buffer whose
//    readers finished at the previous barrier.
//  - W transposed+f64 in d_ws (W64T[c][j]): per tile per wave = 160B contiguous,
//    2 s_loads, wave-uniform (readfirstlane on wave id).
//  - f64 products/accumulation/recurrence unchanged (absmax==0 in R1/R3/R4/R5;
//    the mem>1.0 threshold crossings are the correctness hazard).

constexpr int ROWS  = 65536;
constexpr int COLS  = 784;
constexpr int NOUT  = 10;
constexpr int STEPS = 10;

constexpr int BR   = 64;          // rows per block (thread r owns one row)
constexpr int TW   = 16;          // tile width (784 = 49*16)
constexpr int NT   = COLS / TW;   // 49 tiles
constexpr int PADW = TW + 1;      // 17: odd word stride -> conflict-free b32 reads
constexpr int NH   = 8;           // column octants (= waves per block)
constexpr int CPH  = TW / NH;     // 2 cols per thread per tile
constexpr int NF4  = BR * TW / 4; // 256 float4 per tile

__global__ void w_prep(const float* __restrict__ W, double* __restrict__ W64T) {
    int i = blockIdx.x * 256 + threadIdx.x;   // i = c*10 + j
    if (i < NOUT * COLS) {
        int c = i / NOUT, j = i - c * NOUT;
        W64T[i] = (double)W[(size_t)j * COLS + c];
    }
}

__global__ __launch_bounds__(512, 8)
void snn_fused(const float* __restrict__ x, const double* __restrict__ W64T,
               float* __restrict__ out) {
    // union: [2][BR][PADW] f32 x-tiles (8704B) / [NH][BR][NOUT] f64 combine (40960B)
    __shared__ __align__(16) char smem[NH * BR * NOUT * 8];
    float*  tile = reinterpret_cast<float*>(smem);
    double* comb = reinterpret_cast<double*>(smem);

    const int tid  = threadIdx.x;
    const int r    = tid & (BR - 1);
    const int hu   = __builtin_amdgcn_readfirstlane(tid >> 6);  // wave id = col octant
    const size_t row0 = (size_t)blockIdx.x * BR;

    const float* xblk = x + row0 * COLS;
    const int rr = tid >> 2, c4 = tid & 3;    // staging coords (threads 0..255)

    auto issue = [&](int t, float4& v) {
        if (tid < NF4)
            v = *reinterpret_cast<const float4*>(xblk + (size_t)rr * COLS + t * TW + c4 * 4);
    };
    auto wlds = [&](int b, const float4& v) {
        if (tid < NF4) {
            float* p = tile + b * (BR * PADW) + rr * PADW + c4 * 4;
            p[0] = v.x; p[1] = v.y; p[2] = v.z; p[3] = v.w;
        }
    };

    double acc[NOUT];
    #pragma unroll
    for (int j = 0; j < NOUT; ++j) acc[j] = 0.0;

    // prologue: tile0 -> LDS; tiles 1,2 -> registers (in flight / landed)
    float4 rT, rA, rB, rC;
    issue(0, rT); wlds(0, rT);
    issue(1, rA);
    issue(2, rB);
    __syncthreads();

    for (int t = 0; t < NT; ++t) {
        // invariant: rA = tile t+1, rB = tile t+2 (both issued >=1 iter ago)
        if (t + 1 < NT) wlds((t + 1) & 1, rA);  // counted vmcnt: rB/rC stay in flight
        if (t + 3 < NT) issue(t + 3, rC);

        const float*  src = tile + (t & 1) * (BR * PADW) + r * PADW + hu * CPH;
        const double* wb  = W64T + (size_t)(t * TW + hu * CPH) * NOUT;  // 160B, 2 s_loads
        #pragma unroll
        for (int c = 0; c < CPH; ++c) {
            double xd = (double)src[c];         // ds_read_b32 + cvt (1 per 10 FMA)
            #pragma unroll
            for (int j = 0; j < NOUT; ++j)
                acc[j] = fma(xd, wb[c * NOUT + j], acc[j]);
        }

        __syncthreads();                        // single barrier per tile
        rA = rB; rB = rC;                       // static rotation (no runtime indexing)
    }

    // combine 8 octant-partials per (row, j), then run the recurrence
    #pragma unroll
    for (int j = 0; j < NOUT; ++j)
        comb[(hu * BR + r) * NOUT + j] = acc[j];
    __syncthreads();

    for (int i = tid; i < BR * NOUT; i += 512) {   // 640 outputs, 512 threads
        double c0 = comb[i]                  + comb[BR * NOUT + i];
        double c1 = comb[2 * BR * NOUT + i]  + comb[3 * BR * NOUT + i];
        double c2 = comb[4 * BR * NOUT + i]  + comb[5 * BR * NOUT + i];
        double c3 = comb[6 * BR * NOUT + i]  + comb[7 * BR * NOUT + i];
        double cur = (c0 + c1) + (c2 + c3);

        double mem = 0.0, spk = 0.0, s = 0.0;
        #pragma unroll
        for (int st = 0; st < STEPS; ++st) {
            mem = 0.95 * mem + cur - spk;       // reset-by-subtraction, thr=1.0
            spk = (mem > 1.0) ? 1.0 : 0.0;
            s  += spk;
        }
        out[row0 * NOUT + i] = (float)s;        // 2560B coalesced per block
    }
}

extern "C" void kernel_launch(void* const* d_in, const int* in_sizes, int n_in,
                              void* d_out, int out_size, void* d_ws, size_t ws_size,
                              hipStream_t stream) {
    const float* x = (const float*)d_in[0];
    const float* W = (const float*)d_in[1];
    float*  out  = (float*)d_out;
    double* W64T = (double*)d_ws;   // 7840 * 8B = 62.7 KB

    hipLaunchKernelGGL(w_prep, dim3((NOUT * COLS + 255) / 256), dim3(256), 0, stream, W, W64T);
    hipLaunchKernelGGL(snn_fused, dim3(ROWS / BR), dim3(512), 0, stream, x, W64T, out);
}